// Round 9
// baseline (698.504 us; speedup 1.0000x reference)
//
#include <hip/hip_runtime.h>
#include <math.h>

#define T_   256
#define B_   32
#define N_   16
#define F_   128
#define H_   256
#define BN_  512          // B*N
#define CL_  32           // chunk length
#define NC_  8            // number of chunks (T_/CL_)

typedef __attribute__((ext_vector_type(8))) short  bf16x8;
typedef __attribute__((ext_vector_type(4))) float  f32x4;
typedef __attribute__((ext_vector_type(4))) unsigned short u16x4;

// ---- workspace layout (bytes) ----
#define OFF_H1   0ULL                        // f32 [NC][BN][H]   4 MB
#define OFF_HIN  4194304ULL                  // f32 [NC][BN][H]   4 MB
#define OFF_WBF  8388608ULL                  // bf16 W_hh [768][256]  384 KB
#define OFF_WIB  8781824ULL                  // bf16 W_ih [768][128]  192 KB
#define OFF_DM   8978432ULL                  // u32 [NC][BN]      16 KB
#define WS_NEED  8994816ULL

__device__ __forceinline__ unsigned short f2bf(float f) {   // RNE float->bf16
    union { float f; unsigned u; } v; v.f = f;
    unsigned u = v.u + 0x7FFFu + ((v.u >> 16) & 1u);
    return (unsigned short)(u >> 16);
}
__device__ __forceinline__ float bf2f(unsigned short h) {
    union { unsigned u; float f; } v; v.u = ((unsigned)h) << 16;
    return v.f;
}
__device__ __forceinline__ bf16x8 load_pack8(const float* __restrict__ p) {
    f32x4 a = *(const f32x4*)p;
    f32x4 b = *(const f32x4*)(p + 4);
    bf16x8 r;
    r[0]=(short)f2bf(a[0]); r[1]=(short)f2bf(a[1]); r[2]=(short)f2bf(a[2]); r[3]=(short)f2bf(a[3]);
    r[4]=(short)f2bf(b[0]); r[5]=(short)f2bf(b[1]); r[6]=(short)f2bf(b[2]); r[7]=(short)f2bf(b[3]);
    return r;
}
__device__ __forceinline__ float sigmoidf_(float x) { return 1.0f / (1.0f + __expf(-x)); }
__device__ __forceinline__ float tanhf_(float x)    { return 1.0f - 2.0f / (__expf(2.0f * x) + 1.0f); }

// Pin a bf16x8 fragment to the AGPR class (empty asm; builtin MFMA reads A
// from AGPR directly — AV operand class — with compiler-managed hazards).
__device__ __forceinline__ bf16x8 pin_a(bf16x8 v) {
    bf16x8 r;
    asm("" : "=a"(r) : "0"(v));
    return r;
}

// LDS-only barrier: waits ds ops, leaves global loads/stores in flight.
#define LDS_BARRIER() asm volatile("s_waitcnt lgkmcnt(0)\n\ts_barrier" ::: "memory")

// ---------------------------------------------------------------------------
// prep: wbf = bf16(W_hh); wib = bf16(W_ih); dm = done mask per (chunk, seq)
// ---------------------------------------------------------------------------
__global__ __launch_bounds__(512)
void prep_kernel(const float* __restrict__ W_hh, const float* __restrict__ W_ih,
                 const int* __restrict__ dones,
                 unsigned short* __restrict__ wbf, unsigned short* __restrict__ wib,
                 unsigned int* __restrict__ dm)
{
    const int bid = blockIdx.x, tid = threadIdx.x;
    if (bid < 96) {                                  // W_hh: 49152 f32x4 units
        const int i4 = bid * 512 + tid;
        f32x4 w = ((const f32x4*)W_hh)[i4];
        u16x4 o;
        #pragma unroll
        for (int q = 0; q < 4; ++q) o[q] = f2bf(w[q]);
        ((u16x4*)wbf)[i4] = o;
    } else if (bid < 144) {                          // W_ih: 24576 f32x4 units
        const int i4 = (bid - 96) * 512 + tid;
        f32x4 w = ((const f32x4*)W_ih)[i4];
        u16x4 o;
        #pragma unroll
        for (int q = 0; q < 4; ++q) o[q] = f2bf(w[q]);
        ((u16x4*)wib)[i4] = o;
    } else {                                         // dm: 4096 entries
        const int u = (bid - 144) * 512 + tid;
        const int c = u >> 9, s = u & 511;
        unsigned m = 0;
        #pragma unroll
        for (int k = 0; k < CL_; ++k)
            m |= (dones[(c * CL_ + k) * BN_ + s] ? 1u : 0u) << k;
        dm[c * BN_ + s] = m;
    }
}

// ---------------------------------------------------------------------------
// Fused recurrent core (shared by pass1/pass3): 512 threads = 8 waves.
// Wave w owns j in [32w, 32w+32). Per step, per wave:
//   acc = biases + W_ih.x_t (24 MFMA, K=128) + W_hh.h_t (48 MFMA, K=256)
// n-gate keeps x-part and h-part in separate accumulators.
// W_hh frags (48) + W_ih frags for ktx 0,1 (12) pinned to AGPR = 240 AGPR.
// W_ih frags for ktx 2,3 loaded from L2 each step (stationary addresses).
// x-tile double-buffered in XOR-swizzled LDS; LDS-only barrier per step.
// ---------------------------------------------------------------------------
__global__ __launch_bounds__(512, 1)
void pass1_kernel(const float* __restrict__ x,
                  const unsigned int*  __restrict__ dm,
                  const unsigned short* __restrict__ wbf,
                  const unsigned short* __restrict__ wib,
                  const float* __restrict__ b_ih,
                  const float* __restrict__ b_hh,
                  float* __restrict__ h1)
{
    __shared__ __align__(16) unsigned short hT[2][8][4][16][8];   // 16 KB
    __shared__ __align__(16) unsigned short xb[2][16][128];       // 8 KB (swz)
    __shared__ float sL[4][256];                                  // 4 KB

    const int tid  = threadIdx.x;
    const int wave = tid >> 6, lane = tid & 63;
    const int lr = lane & 15, lg = lane >> 4;
    const int c   = blockIdx.x >> 5;            // 0..NC_-2
    const int bn0 = (blockIdx.x & 31) * 16;
    const int jb  = wave * 32;

    const unsigned m = dm[c * BN_ + bn0 + lr];
    if (__ballot(m != 0) == 0ULL) return;       // uniform: all waves agree

    int last = m ? (31 - __builtin_clz(m)) : 31;
    #pragma unroll
    for (int w = 1; w < 16; w <<= 1) last = min(last, __shfl_xor(last, w));

    // seeds: sL rows = {r: bi+bh, z: bi+bh, nx: bi, nh: bh}
    #pragma unroll
    for (int u = tid; u < 1024; u += 512) {
        const int g4 = u >> 8, j = u & 255;
        float v;
        if      (g4 == 0) v = b_ih[j]        + b_hh[j];
        else if (g4 == 1) v = b_ih[H_ + j]   + b_hh[H_ + j];
        else if (g4 == 2) v = b_ih[2*H_ + j];
        else              v = b_hh[2*H_ + j];
        sL[g4][j] = v;
    }

    ((bf16x8*)hT)[tid] = (bf16x8)(short)0;      // zero hT[0]

    // stage x[c*CL+last] -> xb[0] (8 KB contiguous read, XOR-swizzled write)
    {
        f32x4 v = *(const f32x4*)(x + (size_t)(c*CL_ + last) * BN_ * F_
                                    + (size_t)bn0 * F_ + tid * 4);
        u16x4 o;
        #pragma unroll
        for (int q = 0; q < 4; ++q) o[q] = f2bf(v[q]);
        const unsigned boff = (((unsigned)(tid >> 5)) * 256 + (tid & 31) * 8)
                              ^ ((((unsigned)(tid >> 5)) & 7) << 4);
        *(u16x4*)((char*)&xb[0][0][0] + boff) = o;
    }

    f32x4 hp[2] = {(f32x4){0,0,0,0}, (f32x4){0,0,0,0}};

    // AGPR-stationary weights
    bf16x8 wfa[6][8];                            // W_hh
    #pragma unroll
    for (int mt = 0; mt < 6; ++mt) {
        const int row = (mt >> 1) * H_ + jb + (mt & 1) * 16 + lr;
        #pragma unroll
        for (int kt = 0; kt < 8; ++kt)
            wfa[mt][kt] = pin_a(*(const bf16x8*)(wbf + (size_t)row * H_ + kt*32 + lg*8));
    }
    bf16x8 wip[2][6];                            // W_ih ktx 0,1
    #pragma unroll
    for (int k2 = 0; k2 < 2; ++k2)
        #pragma unroll
        for (int mt = 0; mt < 6; ++mt) {
            const int row = (mt >> 1) * H_ + jb + (mt & 1) * 16 + lr;
            wip[k2][mt] = pin_a(*(const bf16x8*)(wib + (size_t)row * F_ + k2*32 + lg*8));
        }
    __syncthreads();

    int buf = 0, par = 0;
    for (int t = last; t < CL_; ++t) {
        // 1. issue next x-tile stage load (clamped at tail)
        const int tn = (t + 1 < CL_) ? t + 1 : t;
        f32x4 sv = *(const f32x4*)(x + (size_t)(c*CL_ + tn) * BN_ * F_
                                     + (size_t)bn0 * F_ + tid * 4);
        // 2. issue W_ih dynamic frags (ktx 2,3) — pure L2 hits
        bf16x8 wid[2][6];
        #pragma unroll
        for (int k2 = 0; k2 < 2; ++k2)
            #pragma unroll
            for (int mt = 0; mt < 6; ++mt) {
                const int row = (mt >> 1) * H_ + jb + (mt & 1) * 16 + lr;
                wid[k2][mt] = *(const bf16x8*)(wib + (size_t)row * F_ + (2+k2)*32 + lg*8);
            }

        const int d = (m >> t) & 1;
        const short dms = (short)(d ? 0 : -1);

        // 3. seed accumulators: [r0,r1,z0,z1,nx0,nx1,nh0,nh1]
        f32x4 acc[8];
        #pragma unroll
        for (int g2 = 0; g2 < 4; ++g2)
            #pragma unroll
            for (int ms = 0; ms < 2; ++ms)
                acc[g2*2 + ms] = *(const f32x4*)&sL[g2][jb + ms*16 + lg*4];

        // 4. h-phase: W_hh . h  (n -> nh accumulators)
        #pragma unroll
        for (int kt = 0; kt < 8; ++kt) {
            bf16x8 hv = *(const bf16x8*)&hT[buf][kt][lg][lr][0];
            hv = hv & dms;
            #pragma unroll
            for (int mt = 0; mt < 6; ++mt) {
                const int tgt = (mt < 4) ? mt : mt + 2;
                acc[tgt] = __builtin_amdgcn_mfma_f32_16x16x32_bf16(wfa[mt][kt], hv, acc[tgt], 0, 0, 0);
            }
        }
        // 5. x-phase: W_ih . x  (n -> nx accumulators = acc[mt])
        #pragma unroll
        for (int ktx = 0; ktx < 2; ++ktx) {
            const unsigned boff = ((unsigned)(lr*256 + ktx*64 + lg*16)) ^ (((unsigned)(lr & 7)) << 4);
            bf16x8 xf = *(const bf16x8*)((const char*)&xb[par][0][0] + boff);
            #pragma unroll
            for (int mt = 0; mt < 6; ++mt)
                acc[mt] = __builtin_amdgcn_mfma_f32_16x16x32_bf16(wip[ktx][mt], xf, acc[mt], 0, 0, 0);
        }
        #pragma unroll
        for (int k2 = 0; k2 < 2; ++k2) {
            const unsigned boff = ((unsigned)(lr*256 + (k2+2)*64 + lg*16)) ^ (((unsigned)(lr & 7)) << 4);
            bf16x8 xf = *(const bf16x8*)((const char*)&xb[par][0][0] + boff);
            #pragma unroll
            for (int mt = 0; mt < 6; ++mt)
                acc[mt] = __builtin_amdgcn_mfma_f32_16x16x32_bf16(wid[k2][mt], xf, acc[mt], 0, 0, 0);
        }

        // 6. epilogue
        #pragma unroll
        for (int ms = 0; ms < 2; ++ms) {
            const int jq = jb + ms*16 + lg*4;
            u16x4 hb;
            #pragma unroll
            for (int q = 0; q < 4; ++q) {
                float r = sigmoidf_(acc[0 + ms][q]);
                float z = sigmoidf_(acc[2 + ms][q]);
                float n = tanhf_(acc[4 + ms][q] + r * acc[6 + ms][q]);
                float hpv = d ? 0.0f : hp[ms][q];
                float hn2 = n + z * (hpv - n);
                hp[ms][q] = hn2;
                hb[q] = f2bf(hn2);
            }
            *(u16x4*)&hT[buf ^ 1][jq >> 5][(jq >> 3) & 3][lr][jq & 7] = hb;
        }
        // 7. write staged x-tile for t+1 (ds_write waits its load via vmcnt)
        {
            u16x4 o;
            #pragma unroll
            for (int q = 0; q < 4; ++q) o[q] = f2bf(sv[q]);
            const unsigned boff = (((unsigned)(tid >> 5)) * 256 + (tid & 31) * 8)
                                  ^ ((((unsigned)(tid >> 5)) & 7) << 4);
            *(u16x4*)((char*)&xb[par ^ 1][0][0] + boff) = o;
        }
        LDS_BARRIER();
        buf ^= 1; par ^= 1;
    }

    #pragma unroll
    for (int ms = 0; ms < 2; ++ms)
        *(f32x4*)(h1 + ((size_t)c * BN_ + bn0 + lr) * H_ + jb + ms*16 + lg*4) = hp[ms];
}

// ---------------------------------------------------------------------------
// pass2: chain h across chunks. Copy when chunk has a done; rare VALU GRU
// (xg recomputed on the fly from x and wib).
// ---------------------------------------------------------------------------
__global__ __launch_bounds__(256)
void pass2_kernel(const float* __restrict__ x,
                  const unsigned int*  __restrict__ dm,
                  const unsigned short* __restrict__ wbf,
                  const unsigned short* __restrict__ wib,
                  const float* __restrict__ b_ih,
                  const float* __restrict__ b_hh,
                  const float* __restrict__ h0,
                  const float* __restrict__ h1,
                  float* __restrict__ hin)
{
    __shared__ unsigned short hsb[H_];
    __shared__ float xrL[F_];
    const int s = blockIdx.x, j = threadIdx.x;
    float h = h0[(size_t)s * H_ + j];
    const float bir = b_ih[j],      bhr = b_hh[j];
    const float biz = b_ih[H_ + j], bhz = b_hh[H_ + j];
    const float bin = b_ih[2*H_+j], bhn = b_hh[2*H_ + j];

    for (int c = 0; c < NC_; ++c) {
        hin[((size_t)c * BN_ + s) * H_ + j] = h;
        if (c == NC_ - 1) break;
        const unsigned m = dm[c * BN_ + s];         // block-uniform
        if (m) {
            h = h1[((size_t)c * BN_ + s) * H_ + j];
        } else {
            for (int t = 0; t < CL_; ++t) {
                const int tt = c * CL_ + t;
                hsb[j] = f2bf(h);
                if (j < F_) xrL[j] = x[(size_t)tt * BN_ * F_ + (size_t)s * F_ + j];
                __syncthreads();
                float a0 = 0.f, a1 = 0.f, a2 = 0.f;
                for (int k = 0; k < H_; ++k) {
                    float hk = bf2f(hsb[k]);
                    a0 = fmaf(bf2f(wbf[(size_t)j * H_ + k]),          hk, a0);
                    a1 = fmaf(bf2f(wbf[(size_t)(H_ + j) * H_ + k]),   hk, a1);
                    a2 = fmaf(bf2f(wbf[(size_t)(2*H_ + j) * H_ + k]), hk, a2);
                }
                float g0 = 0.f, g1 = 0.f, g2 = 0.f;
                for (int f = 0; f < F_; ++f) {
                    float xf = xrL[f];
                    g0 = fmaf(bf2f(wib[(size_t)j * F_ + f]),          xf, g0);
                    g1 = fmaf(bf2f(wib[(size_t)(H_ + j) * F_ + f]),   xf, g1);
                    g2 = fmaf(bf2f(wib[(size_t)(2*H_ + j) * F_ + f]), xf, g2);
                }
                float r = sigmoidf_(g0 + bir + a0 + bhr);
                float z = sigmoidf_(g1 + biz + a1 + bhz);
                float n = tanhf_(g2 + bin + r * (a2 + bhn));
                h = n + z * (h - n);
                __syncthreads();
            }
        }
    }
}

// ---------------------------------------------------------------------------
// pass3: from known h_in, compute all outputs. Same fused core + out stores.
// ---------------------------------------------------------------------------
__global__ __launch_bounds__(512, 1)
void pass3_kernel(const float* __restrict__ x,
                  const unsigned int*  __restrict__ dm,
                  const unsigned short* __restrict__ wbf,
                  const unsigned short* __restrict__ wib,
                  const float* __restrict__ b_ih,
                  const float* __restrict__ b_hh,
                  const float* __restrict__ hin,
                  float* __restrict__ out)
{
    __shared__ __align__(16) unsigned short hT[2][8][4][16][8];   // 16 KB
    __shared__ __align__(16) unsigned short xb[2][16][128];       // 8 KB (swz)
    __shared__ float sL[4][256];                                  // 4 KB

    const int tid  = threadIdx.x;
    const int wave = tid >> 6, lane = tid & 63;
    const int lr = lane & 15, lg = lane >> 4;
    const int c   = blockIdx.x >> 5;            // 0..NC_-1
    const int bn0 = (blockIdx.x & 31) * 16;
    const int jb  = wave * 32;

    const unsigned m = dm[c * BN_ + bn0 + lr];

    #pragma unroll
    for (int u = tid; u < 1024; u += 512) {
        const int g4 = u >> 8, j = u & 255;
        float v;
        if      (g4 == 0) v = b_ih[j]        + b_hh[j];
        else if (g4 == 1) v = b_ih[H_ + j]   + b_hh[H_ + j];
        else if (g4 == 2) v = b_ih[2*H_ + j];
        else              v = b_hh[2*H_ + j];
        sL[g4][j] = v;
    }

    // stage h_in bf16 -> hT[0]; hp from hin
    {
        const int col = tid & 15, kb = (tid >> 4) * 8;
        bf16x8 hv = load_pack8(hin + ((size_t)c * BN_ + bn0 + col) * H_ + kb);
        ((bf16x8*)hT)[tid] = hv;
    }
    f32x4 hp[2];
    #pragma unroll
    for (int ms = 0; ms < 2; ++ms)
        hp[ms] = *(const f32x4*)(hin + ((size_t)c * BN_ + bn0 + lr) * H_ + jb + ms*16 + lg*4);

    // stage x[c*CL] -> xb[0]
    {
        f32x4 v = *(const f32x4*)(x + (size_t)(c*CL_) * BN_ * F_
                                    + (size_t)bn0 * F_ + tid * 4);
        u16x4 o;
        #pragma unroll
        for (int q = 0; q < 4; ++q) o[q] = f2bf(v[q]);
        const unsigned boff = (((unsigned)(tid >> 5)) * 256 + (tid & 31) * 8)
                              ^ ((((unsigned)(tid >> 5)) & 7) << 4);
        *(u16x4*)((char*)&xb[0][0][0] + boff) = o;
    }

    bf16x8 wfa[6][8];
    #pragma unroll
    for (int mt = 0; mt < 6; ++mt) {
        const int row = (mt >> 1) * H_ + jb + (mt & 1) * 16 + lr;
        #pragma unroll
        for (int kt = 0; kt < 8; ++kt)
            wfa[mt][kt] = pin_a(*(const bf16x8*)(wbf + (size_t)row * H_ + kt*32 + lg*8));
    }
    bf16x8 wip[2][6];
    #pragma unroll
    for (int k2 = 0; k2 < 2; ++k2)
        #pragma unroll
        for (int mt = 0; mt < 6; ++mt) {
            const int row = (mt >> 1) * H_ + jb + (mt & 1) * 16 + lr;
            wip[k2][mt] = pin_a(*(const bf16x8*)(wib + (size_t)row * F_ + k2*32 + lg*8));
        }
    __syncthreads();

    float* op = out + ((size_t)(c*CL_) * BN_ + bn0 + lr) * H_ + jb + lg*4;
    const size_t ostep = (size_t)BN_ * H_;

    int buf = 0, par = 0;
    for (int t = 0; t < CL_; ++t) {
        const int tn = (t + 1 < CL_) ? t + 1 : t;
        f32x4 sv = *(const f32x4*)(x + (size_t)(c*CL_ + tn) * BN_ * F_
                                     + (size_t)bn0 * F_ + tid * 4);
        bf16x8 wid[2][6];
        #pragma unroll
        for (int k2 = 0; k2 < 2; ++k2)
            #pragma unroll
            for (int mt = 0; mt < 6; ++mt) {
                const int row = (mt >> 1) * H_ + jb + (mt & 1) * 16 + lr;
                wid[k2][mt] = *(const bf16x8*)(wib + (size_t)row * F_ + (2+k2)*32 + lg*8);
            }

        const int d = (m >> t) & 1;
        const short dms = (short)(d ? 0 : -1);

        f32x4 acc[8];
        #pragma unroll
        for (int g2 = 0; g2 < 4; ++g2)
            #pragma unroll
            for (int ms = 0; ms < 2; ++ms)
                acc[g2*2 + ms] = *(const f32x4*)&sL[g2][jb + ms*16 + lg*4];

        #pragma unroll
        for (int kt = 0; kt < 8; ++kt) {
            bf16x8 hv = *(const bf16x8*)&hT[buf][kt][lg][lr][0];
            hv = hv & dms;
            #pragma unroll
            for (int mt = 0; mt < 6; ++mt) {
                const int tgt = (mt < 4) ? mt : mt + 2;
                acc[tgt] = __builtin_amdgcn_mfma_f32_16x16x32_bf16(wfa[mt][kt], hv, acc[tgt], 0, 0, 0);
            }
        }
        #pragma unroll
        for (int ktx = 0; ktx < 2; ++ktx) {
            const unsigned boff = ((unsigned)(lr*256 + ktx*64 + lg*16)) ^ (((unsigned)(lr & 7)) << 4);
            bf16x8 xf = *(const bf16x8*)((const char*)&xb[par][0][0] + boff);
            #pragma unroll
            for (int mt = 0; mt < 6; ++mt)
                acc[mt] = __builtin_amdgcn_mfma_f32_16x16x32_bf16(wip[ktx][mt], xf, acc[mt], 0, 0, 0);
        }
        #pragma unroll
        for (int k2 = 0; k2 < 2; ++k2) {
            const unsigned boff = ((unsigned)(lr*256 + (k2+2)*64 + lg*16)) ^ (((unsigned)(lr & 7)) << 4);
            bf16x8 xf = *(const bf16x8*)((const char*)&xb[par][0][0] + boff);
            #pragma unroll
            for (int mt = 0; mt < 6; ++mt)
                acc[mt] = __builtin_amdgcn_mfma_f32_16x16x32_bf16(wid[k2][mt], xf, acc[mt], 0, 0, 0);
        }

        f32x4 hnew4[2];
        #pragma unroll
        for (int ms = 0; ms < 2; ++ms) {
            const int jq = jb + ms*16 + lg*4;
            u16x4 hb;
            #pragma unroll
            for (int q = 0; q < 4; ++q) {
                float r = sigmoidf_(acc[0 + ms][q]);
                float z = sigmoidf_(acc[2 + ms][q]);
                float n = tanhf_(acc[4 + ms][q] + r * acc[6 + ms][q]);
                float hpv = d ? 0.0f : hp[ms][q];
                float hn2 = n + z * (hpv - n);
                hp[ms][q] = hn2;
                hnew4[ms][q] = hn2;
                hb[q] = f2bf(hn2);
            }
            *(u16x4*)&hT[buf ^ 1][jq >> 5][(jq >> 3) & 3][lr][jq & 7] = hb;
        }
        #pragma unroll
        for (int ms = 0; ms < 2; ++ms)
            *(f32x4*)(op + ms*16) = hnew4[ms];
        {
            u16x4 o;
            #pragma unroll
            for (int q = 0; q < 4; ++q) o[q] = f2bf(sv[q]);
            const unsigned boff = (((unsigned)(tid >> 5)) * 256 + (tid & 31) * 8)
                                  ^ ((((unsigned)(tid >> 5)) & 7) << 4);
            *(u16x4*)((char*)&xb[par ^ 1][0][0] + boff) = o;
        }
        LDS_BARRIER();
        buf ^= 1; par ^= 1;
        op += ostep;
    }

    if (c == NC_ - 1) {
        #pragma unroll
        for (int ms = 0; ms < 2; ++ms)
            *(f32x4*)(out + (size_t)T_ * BN_ * H_ + (size_t)(bn0 + lr) * H_
                      + jb + ms*16 + lg*4) = hp[ms];
    }
}

// ---------------------------------------------------------------------------
// Fallback (ws too small): fp32 VALU persistent kernel (correct, slow)
// ---------------------------------------------------------------------------
#define SPB 4
__global__ __launch_bounds__(256, 1)
void slotgru_fallback(const float* __restrict__ x, const int* __restrict__ dones,
                      const float* __restrict__ h0, const float* __restrict__ W_ih,
                      const float* __restrict__ W_hh, const float* __restrict__ b_ih,
                      const float* __restrict__ b_hh, float* __restrict__ out)
{
    __shared__ __align__(16) float xs[SPB][F_];
    __shared__ __align__(16) float hs[SPB][H_];
    const int j = threadIdx.x, bn0 = blockIdx.x * SPB;
    const float bi0 = b_ih[j], bi1 = b_ih[H_ + j], bi2 = b_ih[2*H_ + j];
    const float bh0 = b_hh[j], bh1 = b_hh[H_ + j], bh2 = b_hh[2*H_ + j];
    const float4* wi0 = (const float4*)(W_ih + (size_t)j * F_);
    const float4* wi1 = (const float4*)(W_ih + (size_t)(H_ + j) * F_);
    const float4* wi2 = (const float4*)(W_ih + (size_t)(2*H_ + j) * F_);
    const float4* wh0 = (const float4*)(W_hh + (size_t)j * H_);
    const float4* wh1 = (const float4*)(W_hh + (size_t)(H_ + j) * H_);
    const float4* wh2 = (const float4*)(W_hh + (size_t)(2*H_ + j) * H_);
    float hreg[SPB];
    #pragma unroll
    for (int s = 0; s < SPB; ++s) { float h = h0[(size_t)(bn0+s)*H_ + j]; hreg[s]=h; hs[s][j]=h; }
    for (int t = 0; t < T_; ++t) {
        int d[SPB];
        #pragma unroll
        for (int s = 0; s < SPB; ++s) d[s] = dones[(size_t)t*BN_ + bn0 + s];
        const float* xsrc = x + (size_t)((size_t)t*BN_ + bn0) * F_;
        ((float*)xs)[j] = xsrc[j]; ((float*)xs)[j+256] = xsrc[j+256];
        #pragma unroll
        for (int s = 0; s < SPB; ++s) if (d[s]) hs[s][j] = 0.0f;
        __syncthreads();
        float ax0[SPB]={0,0,0,0}, ax1[SPB]={0,0,0,0}, ax2[SPB]={0,0,0,0};
        #pragma unroll 8
        for (int cc = 0; cc < F_/4; ++cc) {
            float4 w0=wi0[cc], w1=wi1[cc], w2=wi2[cc];
            #pragma unroll
            for (int s = 0; s < SPB; ++s) {
                float4 xv = ((const float4*)xs[s])[cc];
                ax0[s]=fmaf(w0.x,xv.x,fmaf(w0.y,xv.y,fmaf(w0.z,xv.z,fmaf(w0.w,xv.w,ax0[s]))));
                ax1[s]=fmaf(w1.x,xv.x,fmaf(w1.y,xv.y,fmaf(w1.z,xv.z,fmaf(w1.w,xv.w,ax1[s]))));
                ax2[s]=fmaf(w2.x,xv.x,fmaf(w2.y,xv.y,fmaf(w2.z,xv.z,fmaf(w2.w,xv.w,ax2[s]))));
            }
        }
        float ah0[SPB]={0,0,0,0}, ah1[SPB]={0,0,0,0}, ah2[SPB]={0,0,0,0};
        if (!(d[0]&&d[1]&&d[2]&&d[3])) {
            #pragma unroll 4
            for (int cc = 0; cc < H_/4; ++cc) {
                float4 w0=wh0[cc], w1=wh1[cc], w2=wh2[cc];
                #pragma unroll
                for (int s = 0; s < SPB; ++s) if (!d[s]) {
                    float4 hv = ((const float4*)hs[s])[cc];
                    ah0[s]=fmaf(w0.x,hv.x,fmaf(w0.y,hv.y,fmaf(w0.z,hv.z,fmaf(w0.w,hv.w,ah0[s]))));
                    ah1[s]=fmaf(w1.x,hv.x,fmaf(w1.y,hv.y,fmaf(w1.z,hv.z,fmaf(w1.w,hv.w,ah1[s]))));
                    ah2[s]=fmaf(w2.x,hv.x,fmaf(w2.y,hv.y,fmaf(w2.z,hv.z,fmaf(w2.w,hv.w,ah2[s]))));
                }
            }
        }
        float hnew[SPB];
        #pragma unroll
        for (int s = 0; s < SPB; ++s) {
            float hpv = d[s] ? 0.0f : hreg[s];
            float r = sigmoidf_(ax0[s] + bi0 + ah0[s] + bh0);
            float z = sigmoidf_(ax1[s] + bi1 + ah1[s] + bh1);
            float n = tanhf_(ax2[s] + bi2 + r * (ah2[s] + bh2));
            hnew[s] = (1.0f - z) * n + z * hpv;
        }
        __syncthreads();
        #pragma unroll
        for (int s = 0; s < SPB; ++s) {
            hs[s][j] = hnew[s]; hreg[s] = hnew[s];
            out[(size_t)((size_t)t*BN_ + bn0 + s) * H_ + j] = hnew[s];
        }
    }
    #pragma unroll
    for (int s = 0; s < SPB; ++s)
        out[(size_t)T_*BN_*H_ + (size_t)(bn0+s)*H_ + j] = hreg[s];
}

extern "C" void kernel_launch(void* const* d_in, const int* in_sizes, int n_in,
                              void* d_out, int out_size, void* d_ws, size_t ws_size,
                              hipStream_t stream) {
    const float* x     = (const float*)d_in[0];
    const int*   dones = (const int*)  d_in[1];
    const float* h0    = (const float*)d_in[2];
    const float* W_ih  = (const float*)d_in[3];
    const float* W_hh  = (const float*)d_in[4];
    const float* b_ih  = (const float*)d_in[5];
    const float* b_hh  = (const float*)d_in[6];
    float*       out   = (float*)d_out;

    if (ws_size >= WS_NEED) {
        char* ws = (char*)d_ws;
        float*          h1  = (float*)(ws + OFF_H1);
        float*          hin = (float*)(ws + OFF_HIN);
        unsigned short* wbf = (unsigned short*)(ws + OFF_WBF);
        unsigned short* wib = (unsigned short*)(ws + OFF_WIB);
        unsigned int*   dmm = (unsigned int*)(ws + OFF_DM);

        hipLaunchKernelGGL(prep_kernel, dim3(152), dim3(512), 0, stream,
                           W_hh, W_ih, dones, wbf, wib, dmm);
        hipLaunchKernelGGL(pass1_kernel, dim3((NC_ - 1) * 32), dim3(512), 0, stream,
                           x, dmm, wbf, wib, b_ih, b_hh, h1);
        hipLaunchKernelGGL(pass2_kernel, dim3(BN_), dim3(256), 0, stream,
                           x, dmm, wbf, wib, b_ih, b_hh, h0, h1, hin);
        hipLaunchKernelGGL(pass3_kernel, dim3(NC_ * 32), dim3(512), 0, stream,
                           x, dmm, wbf, wib, b_ih, b_hh, hin, out);
    } else {
        hipLaunchKernelGGL(slotgru_fallback, dim3(BN_ / SPB), dim3(256), 0, stream,
                           x, dones, h0, W_ih, W_hh, b_ih, b_hh, out);
    }
}

// Round 10
// 481.298 us; speedup vs baseline: 1.4513x; 1.4513x over previous
//
#include <hip/hip_runtime.h>
#include <math.h>

#define T_   256
#define B_   32
#define N_   16
#define F_   128
#define H_   256
#define BN_  512          // B*N
#define G3_  768          // 3*H
#define CL_  32           // chunk length
#define NC_  8            // number of chunks (T_/CL_)

typedef __attribute__((ext_vector_type(8))) short  bf16x8;
typedef __attribute__((ext_vector_type(4))) float  f32x4;
typedef __attribute__((ext_vector_type(4))) unsigned short u16x4;

// ---- workspace layout (bytes) ----  (identical to round 6 — known to fit)
#define OFF_H1   0ULL                                   // f32 [NC][BN][H]   4 MB
#define OFF_HIN  4194304ULL                             // f32 [NC][BN][H]   4 MB
#define OFF_WBF  8388608ULL                             // bf16 [768][256]   384 KB
#define OFF_DM   8781824ULL                             // u32 [NC][BN]      16 KB
#define OFF_XG   8798208ULL                             // bf16 xg2 tiled    192 MB
#define WS_NEED  210124800ULL

__device__ __forceinline__ unsigned short f2bf(float f) {   // RNE float->bf16
    union { float f; unsigned u; } v; v.f = f;
    unsigned u = v.u + 0x7FFFu + ((v.u >> 16) & 1u);
    return (unsigned short)(u >> 16);
}
__device__ __forceinline__ float bf2f(unsigned short h) {
    union { unsigned u; float f; } v; v.u = ((unsigned)h) << 16;
    return v.f;
}
__device__ __forceinline__ bf16x8 load_pack8(const float* __restrict__ p) {
    f32x4 a = *(const f32x4*)p;
    f32x4 b = *(const f32x4*)(p + 4);
    bf16x8 r;
    r[0]=(short)f2bf(a[0]); r[1]=(short)f2bf(a[1]); r[2]=(short)f2bf(a[2]); r[3]=(short)f2bf(a[3]);
    r[4]=(short)f2bf(b[0]); r[5]=(short)f2bf(b[1]); r[6]=(short)f2bf(b[2]); r[7]=(short)f2bf(b[3]);
    return r;
}
__device__ __forceinline__ float sigmoidf_(float x) { return 1.0f / (1.0f + __expf(-x)); }
__device__ __forceinline__ float tanhf_(float x)    { return 1.0f - 2.0f / (__expf(2.0f * x) + 1.0f); }

// Pin a bf16x8 fragment to the AGPR class (empty asm; builtin MFMA reads A
// from AGPR directly — AV operand class — with compiler-managed hazards).
__device__ __forceinline__ bf16x8 pin_a(bf16x8 v) {
    bf16x8 r;
    asm("" : "=a"(r) : "0"(v));
    return r;
}

// LDS-only barrier: waits ds ops, leaves global loads/stores in flight.
// Correctness proven in round 8 (passed); round-8 regression was the extra
// prefetch registers, not this barrier.
#define LDS_BARRIER() asm volatile("s_waitcnt lgkmcnt(0)\n\ts_barrier" ::: "memory")

// xg2 tiled layout: u16 index for element (tt, seq, g)
__device__ __forceinline__ size_t xg2_idx(int tt, int seq, int g) {
    return ((((size_t)tt * 32 + (seq >> 4)) * 48 + (g >> 4)) * 64
            + ((g >> 2) & 3) * 16 + (seq & 15)) * 4 + (g & 3);
}

// ---------------------------------------------------------------------------
// xg2 v2: barrier-free, LDS-free input-projection GEMM.
// Grid 8192 compute blocks (256 thr = 4 waves) + 208 fused prep blocks.
// Block = (t, 64-seq group, 192-g region); wave = 48 g x 64 seqs.
// Fragments loaded straight from global (L1 absorbs the 4x intra-block
// x redundancy); output layout identical to round 6.
// ---------------------------------------------------------------------------
__global__ __launch_bounds__(256, 3)
void xg2v2_kernel(const float* __restrict__ x, const float* __restrict__ W_ih,
                  const float* __restrict__ b_ih, const float* __restrict__ b_hh,
                  const float* __restrict__ W_hh, const int* __restrict__ dones,
                  unsigned short* __restrict__ xg2,
                  unsigned short* __restrict__ wbf, unsigned int* __restrict__ dm)
{
    const int tid = threadIdx.x;
    if (blockIdx.x >= 8192) {                       // ---- fused prep ----
        const int bid2 = blockIdx.x - 8192;
        if (bid2 < 192) {                           // W_hh f32 -> bf16
            const int i4 = bid2 * 256 + tid;        // 49152 f32x4 units
            f32x4 w = ((const f32x4*)W_hh)[i4];
            u16x4 o;
            #pragma unroll
            for (int q = 0; q < 4; ++q) o[q] = f2bf(w[q]);
            ((u16x4*)wbf)[i4] = o;
        } else {                                    // done masks (u32, CL=32)
            const int u = (bid2 - 192) * 256 + tid; // 16 blocks x 256 = 4096
            const int c = u >> 9, s = u & 511;
            unsigned m = 0;
            #pragma unroll
            for (int k = 0; k < CL_; ++k)
                m |= (dones[(c * CL_ + k) * BN_ + s] ? 1u : 0u) << k;
            dm[c * BN_ + s] = m;
        }
        return;
    }

    const int wave = tid >> 6, lane = tid & 63;
    const int lr = lane & 15, lg = lane >> 4;
    const int t  = blockIdx.x >> 5;                 // 0..255
    const int sb = (blockIdx.x >> 2) & 7;           // 64-seq group 0..7
    const int g0 = (blockIdx.x & 3) * 192 + wave * 48;

    // W_ih A-fragments: 3 g-tiles x 4 k-tiles (48 VGPR)
    bf16x8 wf[3][4];
    #pragma unroll
    for (int gt = 0; gt < 3; ++gt)
        #pragma unroll
        for (int kt = 0; kt < 4; ++kt)
            wf[gt][kt] = load_pack8(W_ih + (size_t)(g0 + gt*16 + lr) * F_ + kt*32 + lg*8);

    float bv[3][4];
    #pragma unroll
    for (int gt = 0; gt < 3; ++gt)
        #pragma unroll
        for (int q = 0; q < 4; ++q) {
            const int g = g0 + gt*16 + lg*4 + q;
            bv[gt][q] = b_ih[g] + (g < 2*H_ ? b_hh[g] : 0.0f);
        }

    const float* xrow = x + ((size_t)t * BN_ + sb * 64) * F_;

    #pragma unroll
    for (int st = 0; st < 4; ++st) {
        bf16x8 xf[4];                               // B-frags: col = seq
        #pragma unroll
        for (int kt = 0; kt < 4; ++kt)
            xf[kt] = load_pack8(xrow + (size_t)(st*16 + lr) * F_ + kt*32 + lg*8);

        f32x4 acc[3];
        #pragma unroll
        for (int gt = 0; gt < 3; ++gt) acc[gt] = (f32x4){0.f, 0.f, 0.f, 0.f};

        #pragma unroll
        for (int kt = 0; kt < 4; ++kt)
            #pragma unroll
            for (int gt = 0; gt < 3; ++gt)
                acc[gt] = __builtin_amdgcn_mfma_f32_16x16x32_bf16(wf[gt][kt], xf[kt], acc[gt], 0, 0, 0);

        // D: row(g-in-tile) = lg*4+q, col(seq) = lr -> per-lane u16x4, coalesced
        const int sbg = sb * 4 + st;
        #pragma unroll
        for (int gt = 0; gt < 3; ++gt) {
            u16x4 o;
            #pragma unroll
            for (int q = 0; q < 4; ++q) o[q] = f2bf(acc[gt][q] + bv[gt][q]);
            const size_t base = (((size_t)t * 32 + sbg) * 48 + (g0 >> 4) + gt) * 64 + lane;
            *(u16x4*)(xg2 + base * 4) = o;
        }
    }
}

// ---------------------------------------------------------------------------
// Recurrent core (round-6 structure, LDS-only step barrier): 256 thr = 4 waves.
// Wave w owns j in [64w, 64w+64): r+z weights (64 frags) pinned to AGPR,
// n-gate (32 frags) in VGPRs. Weights loaded ONCE per block.
// ---------------------------------------------------------------------------
__global__ __launch_bounds__(256, 1)
void pass1_kernel(const unsigned short* __restrict__ xg2,
                  const unsigned int*  __restrict__ dm,
                  const unsigned short* __restrict__ wbf,
                  const float* __restrict__ b_hh,
                  float* __restrict__ h1)
{
    __shared__ __align__(16) unsigned short hT[2][8][4][16][8];   // 16 KB
    __shared__ __align__(16) float hpL[16][260];                  // 16.6 KB
    __shared__ float bhnL[H_];                                    // 1 KB

    const int tid  = threadIdx.x;
    const int wave = tid >> 6, lane = tid & 63;
    const int lr = lane & 15, lg = lane >> 4;
    const int c   = blockIdx.x >> 5;            // 0..NC_-2
    const int bn0 = (blockIdx.x & 31) * 16;
    const int jb  = wave * 64;

    const unsigned m = dm[c * BN_ + bn0 + lr];
    if (__ballot(m != 0) == 0ULL) return;       // uniform across waves

    int last = m ? (31 - __builtin_clz(m)) : 31;
    #pragma unroll
    for (int w = 1; w < 16; w <<= 1) last = min(last, __shfl_xor(last, w));

    bhnL[tid] = b_hh[2*H_ + tid];
    #pragma unroll
    for (int sweep = 0; sweep < 2; ++sweep)
        ((bf16x8*)hT)[sweep * 256 + tid] = (bf16x8)(short)0;
    #pragma unroll
    for (int sweep = 0; sweep < 4; ++sweep) {
        const int u = sweep * 256 + tid, seq = u >> 6, jq = u & 63;
        *(f32x4*)&hpL[seq][jq * 4] = (f32x4){0.f, 0.f, 0.f, 0.f};
    }

    // r+z gate weights -> AGPR (pinned); n gate -> VGPR
    bf16x8 wfa[8][8];   // mt = g*4+ms, g in {0(r),1(z)}
    bf16x8 wfv[4][8];   // n gate
    #pragma unroll
    for (int mt = 0; mt < 8; ++mt) {
        const int row = (mt >> 2) * H_ + jb + (mt & 3) * 16 + lr;
        #pragma unroll
        for (int kt = 0; kt < 8; ++kt)
            wfa[mt][kt] = pin_a(*(const bf16x8*)(wbf + (size_t)row * H_ + kt*32 + lg*8));
    }
    #pragma unroll
    for (int ms = 0; ms < 4; ++ms) {
        const int row = 2 * H_ + jb + ms * 16 + lr;
        #pragma unroll
        for (int kt = 0; kt < 8; ++kt)
            wfv[ms][kt] = *(const bf16x8*)(wbf + (size_t)row * H_ + kt*32 + lg*8);
    }
    __syncthreads();

    const int sb = bn0 >> 4;
    int buf = 0;
    for (int t = last; t < CL_; ++t) {
        const int tt = c * CL_ + t;
        const int tb = (tt * 32 + sb) * 48;

        u16x4 xv[3][4];
        #pragma unroll
        for (int g = 0; g < 3; ++g)
            #pragma unroll
            for (int ms = 0; ms < 4; ++ms)
                xv[g][ms] = ((const u16x4*)xg2)[(size_t)(tb + g*16 + wave*4 + ms) * 64 + lane];

        const int d = (m >> t) & 1;
        const short dms = (short)(d ? 0 : -1);

        f32x4 acc[12];
        #pragma unroll
        for (int mt = 0; mt < 8; ++mt) acc[mt] = (f32x4){0.f, 0.f, 0.f, 0.f};
        #pragma unroll
        for (int ms = 0; ms < 4; ++ms)                 // n-gate seeded with b_hh_n
            acc[8 + ms] = *(const f32x4*)&bhnL[jb + ms*16 + lg*4];

        #pragma unroll
        for (int kt = 0; kt < 8; ++kt) {
            bf16x8 hv = *(const bf16x8*)&hT[buf][kt][lg][lr][0];
            hv = hv & dms;
            #pragma unroll
            for (int mt = 0; mt < 8; ++mt)
                acc[mt] = __builtin_amdgcn_mfma_f32_16x16x32_bf16(wfa[mt][kt], hv, acc[mt], 0, 0, 0);
            #pragma unroll
            for (int ms = 0; ms < 4; ++ms)
                acc[8 + ms] = __builtin_amdgcn_mfma_f32_16x16x32_bf16(wfv[ms][kt], hv, acc[8 + ms], 0, 0, 0);
        }

        #pragma unroll
        for (int ms = 0; ms < 4; ++ms) {
            const int jq = jb + ms*16 + lg*4;
            f32x4 hp4 = *(const f32x4*)&hpL[lr][jq];
            f32x4 hnew4; u16x4 hb;
            #pragma unroll
            for (int q = 0; q < 4; ++q) {
                float r = sigmoidf_(acc[0 + ms][q] + bf2f(xv[0][ms][q]));
                float z = sigmoidf_(acc[4 + ms][q] + bf2f(xv[1][ms][q]));
                float n = tanhf_(bf2f(xv[2][ms][q]) + r * acc[8 + ms][q]);
                float hpv = d ? 0.0f : hp4[q];
                float hn2 = n + z * (hpv - n);
                hnew4[q] = hn2; hb[q] = f2bf(hn2);
            }
            *(f32x4*)&hpL[lr][jq] = hnew4;
            *(u16x4*)&hT[buf ^ 1][jq >> 5][(jq >> 3) & 3][lr][jq & 7] = hb;
        }
        LDS_BARRIER();                              // no vmcnt drain
        buf ^= 1;
    }

    #pragma unroll
    for (int ms = 0; ms < 4; ++ms) {
        const int jq = jb + ms*16 + lg*4;
        f32x4 hv = *(const f32x4*)&hpL[lr][jq];
        *(f32x4*)(h1 + ((size_t)c * BN_ + bn0 + lr) * H_ + jq) = hv;
    }
}

// ---------------------------------------------------------------------------
// pass2: chain h across chunks. Copy when chunk has a done; rare VALU GRU.
// ---------------------------------------------------------------------------
__global__ __launch_bounds__(256)
void pass2_kernel(const unsigned short* __restrict__ xg2,
                  const unsigned int*  __restrict__ dm,
                  const unsigned short* __restrict__ wbf,
                  const float* __restrict__ b_hh,
                  const float* __restrict__ h0,
                  const float* __restrict__ h1,
                  float* __restrict__ hin)
{
    __shared__ unsigned short hsb[H_];
    const int s = blockIdx.x, j = threadIdx.x;
    float h = h0[(size_t)s * H_ + j];
    const float bhn = b_hh[2*H_ + j];

    for (int c = 0; c < NC_; ++c) {
        hin[((size_t)c * BN_ + s) * H_ + j] = h;
        if (c == NC_ - 1) break;
        const unsigned m = dm[c * BN_ + s];         // block-uniform
        if (m) {
            h = h1[((size_t)c * BN_ + s) * H_ + j];
        } else {
            for (int t = 0; t < CL_; ++t) {
                hsb[j] = f2bf(h);
                __syncthreads();
                float a0 = 0.f, a1 = 0.f, a2 = 0.f;
                for (int k = 0; k < H_; ++k) {
                    float hk = bf2f(hsb[k]);
                    a0 = fmaf(bf2f(wbf[(size_t)j * H_ + k]),          hk, a0);
                    a1 = fmaf(bf2f(wbf[(size_t)(H_ + j) * H_ + k]),   hk, a1);
                    a2 = fmaf(bf2f(wbf[(size_t)(2*H_ + j) * H_ + k]), hk, a2);
                }
                const int tt = c * CL_ + t;
                float xr = bf2f(xg2[xg2_idx(tt, s, j)]);
                float xz = bf2f(xg2[xg2_idx(tt, s, H_ + j)]);
                float xn = bf2f(xg2[xg2_idx(tt, s, 2*H_ + j)]);
                float r = sigmoidf_(a0 + xr);
                float z = sigmoidf_(a1 + xz);
                float n = tanhf_(xn + r * (a2 + bhn));
                h = n + z * (h - n);
                __syncthreads();
            }
        }
    }
}

// ---------------------------------------------------------------------------
// pass3: from known h_in, compute all outputs. Round-6 core + LDS-only barrier
// (out stores issued before the barrier stay in flight — no vmcnt drain).
// ---------------------------------------------------------------------------
__global__ __launch_bounds__(256, 1)
void pass3_kernel(const unsigned short* __restrict__ xg2,
                  const unsigned int*  __restrict__ dm,
                  const unsigned short* __restrict__ wbf,
                  const float* __restrict__ b_hh,
                  const float* __restrict__ hin,
                  float* __restrict__ out)
{
    __shared__ __align__(16) unsigned short hT[2][8][4][16][8];   // 16 KB
    __shared__ __align__(16) float hpL[16][260];                  // 16.6 KB
    __shared__ float bhnL[H_];                                    // 1 KB

    const int tid  = threadIdx.x;
    const int wave = tid >> 6, lane = tid & 63;
    const int lr = lane & 15, lg = lane >> 4;
    const int c   = blockIdx.x >> 5;            // 0..NC_-1
    const int bn0 = (blockIdx.x & 31) * 16;
    const int jb  = wave * 64;

    const unsigned m = dm[c * BN_ + bn0 + lr];

    bhnL[tid] = b_hh[2*H_ + tid];
    // stage h_in: f32 -> hpL, bf16 -> hT[0]
    #pragma unroll
    for (int sweep = 0; sweep < 4; ++sweep) {
        const int u = sweep * 256 + tid, seq = u >> 6, jq = u & 63;
        f32x4 hv = ((const f32x4*)hin)[((size_t)c * BN_ + bn0 + seq) * 64 + jq];
        *(f32x4*)&hpL[seq][jq * 4] = hv;
    }
    #pragma unroll
    for (int sweep = 0; sweep < 2; ++sweep) {
        const int u = sweep * 256 + tid, col = u & 15, kb = (u >> 4) * 8;
        bf16x8 hv = load_pack8(hin + ((size_t)c * BN_ + bn0 + col) * H_ + kb);
        ((bf16x8*)hT)[u] = hv;
    }

    bf16x8 wfa[8][8];
    bf16x8 wfv[4][8];
    #pragma unroll
    for (int mt = 0; mt < 8; ++mt) {
        const int row = (mt >> 2) * H_ + jb + (mt & 3) * 16 + lr;
        #pragma unroll
        for (int kt = 0; kt < 8; ++kt)
            wfa[mt][kt] = pin_a(*(const bf16x8*)(wbf + (size_t)row * H_ + kt*32 + lg*8));
    }
    #pragma unroll
    for (int ms = 0; ms < 4; ++ms) {
        const int row = 2 * H_ + jb + ms * 16 + lr;
        #pragma unroll
        for (int kt = 0; kt < 8; ++kt)
            wfv[ms][kt] = *(const bf16x8*)(wbf + (size_t)row * H_ + kt*32 + lg*8);
    }
    __syncthreads();

    const int sb = bn0 >> 4;
    int buf = 0;
    for (int t = 0; t < CL_; ++t) {
        const int tt = c * CL_ + t;
        const int tb = (tt * 32 + sb) * 48;

        u16x4 xv[3][4];
        #pragma unroll
        for (int g = 0; g < 3; ++g)
            #pragma unroll
            for (int ms = 0; ms < 4; ++ms)
                xv[g][ms] = ((const u16x4*)xg2)[(size_t)(tb + g*16 + wave*4 + ms) * 64 + lane];

        const int d = (m >> t) & 1;
        const short dms = (short)(d ? 0 : -1);

        f32x4 acc[12];
        #pragma unroll
        for (int mt = 0; mt < 8; ++mt) acc[mt] = (f32x4){0.f, 0.f, 0.f, 0.f};
        #pragma unroll
        for (int ms = 0; ms < 4; ++ms)                 // n-gate seeded with b_hh_n
            acc[8 + ms] = *(const f32x4*)&bhnL[jb + ms*16 + lg*4];

        #pragma unroll
        for (int kt = 0; kt < 8; ++kt) {
            bf16x8 hv = *(const bf16x8*)&hT[buf][kt][lg][lr][0];
            hv = hv & dms;
            #pragma unroll
            for (int mt = 0; mt < 8; ++mt)
                acc[mt] = __builtin_amdgcn_mfma_f32_16x16x32_bf16(wfa[mt][kt], hv, acc[mt], 0, 0, 0);
            #pragma unroll
            for (int ms = 0; ms < 4; ++ms)
                acc[8 + ms] = __builtin_amdgcn_mfma_f32_16x16x32_bf16(wfv[ms][kt], hv, acc[8 + ms], 0, 0, 0);
        }

        #pragma unroll
        for (int ms = 0; ms < 4; ++ms) {
            const int jq = jb + ms*16 + lg*4;
            f32x4 hp4 = *(const f32x4*)&hpL[lr][jq];
            f32x4 hnew4; u16x4 hb;
            #pragma unroll
            for (int q = 0; q < 4; ++q) {
                float r = sigmoidf_(acc[0 + ms][q] + bf2f(xv[0][ms][q]));
                float z = sigmoidf_(acc[4 + ms][q] + bf2f(xv[1][ms][q]));
                float n = tanhf_(bf2f(xv[2][ms][q]) + r * acc[8 + ms][q]);
                float hpv = d ? 0.0f : hp4[q];
                float hn2 = n + z * (hpv - n);
                hnew4[q] = hn2; hb[q] = f2bf(hn2);
            }
            *(f32x4*)&hpL[lr][jq] = hnew4;
            *(u16x4*)&hT[buf ^ 1][jq >> 5][(jq >> 3) & 3][lr][jq & 7] = hb;
            *(f32x4*)(out + ((size_t)tt * BN_ + bn0 + lr) * H_ + jq) = hnew4;
        }
        LDS_BARRIER();                              // stores stay in flight
        buf ^= 1;
    }

    if (c == NC_ - 1) {
        #pragma unroll
        for (int ms = 0; ms < 4; ++ms) {
            const int jq = jb + ms*16 + lg*4;
            f32x4 hv = *(const f32x4*)&hpL[lr][jq];
            *(f32x4*)(out + (size_t)T_ * BN_ * H_ + (size_t)(bn0 + lr) * H_ + jq) = hv;
        }
    }
}

// ---------------------------------------------------------------------------
// Fallback (ws too small): fp32 VALU persistent kernel (correct, slow)
// ---------------------------------------------------------------------------
#define SPB 4
__global__ __launch_bounds__(256, 1)
void slotgru_fallback(const float* __restrict__ x, const int* __restrict__ dones,
                      const float* __restrict__ h0, const float* __restrict__ W_ih,
                      const float* __restrict__ W_hh, const float* __restrict__ b_ih,
                      const float* __restrict__ b_hh, float* __restrict__ out)
{
    __shared__ __align__(16) float xs[SPB][F_];
    __shared__ __align__(16) float hs[SPB][H_];
    const int j = threadIdx.x, bn0 = blockIdx.x * SPB;
    const float bi0 = b_ih[j], bi1 = b_ih[H_ + j], bi2 = b_ih[2*H_ + j];
    const float bh0 = b_hh[j], bh1 = b_hh[H_ + j], bh2 = b_hh[2*H_ + j];
    const float4* wi0 = (const float4*)(W_ih + (size_t)j * F_);
    const float4* wi1 = (const float4*)(W_ih + (size_t)(H_ + j) * F_);
    const float4* wi2 = (const float4*)(W_ih + (size_t)(2*H_ + j) * F_);
    const float4* wh0 = (const float4*)(W_hh + (size_t)j * H_);
    const float4* wh1 = (const float4*)(W_hh + (size_t)(H_ + j) * H_);
    const float4* wh2 = (const float4*)(W_hh + (size_t)(2*H_ + j) * H_);
    float hreg[SPB];
    #pragma unroll
    for (int s = 0; s < SPB; ++s) { float h = h0[(size_t)(bn0+s)*H_ + j]; hreg[s]=h; hs[s][j]=h; }
    for (int t = 0; t < T_; ++t) {
        int d[SPB];
        #pragma unroll
        for (int s = 0; s < SPB; ++s) d[s] = dones[(size_t)t*BN_ + bn0 + s];
        const float* xsrc = x + (size_t)((size_t)t*BN_ + bn0) * F_;
        ((float*)xs)[j] = xsrc[j]; ((float*)xs)[j+256] = xsrc[j+256];
        #pragma unroll
        for (int s = 0; s < SPB; ++s) if (d[s]) hs[s][j] = 0.0f;
        __syncthreads();
        float ax0[SPB]={0,0,0,0}, ax1[SPB]={0,0,0,0}, ax2[SPB]={0,0,0,0};
        #pragma unroll 8
        for (int cc = 0; cc < F_/4; ++cc) {
            float4 w0=wi0[cc], w1=wi1[cc], w2=wi2[cc];
            #pragma unroll
            for (int s = 0; s < SPB; ++s) {
                float4 xv = ((const float4*)xs[s])[cc];
                ax0[s]=fmaf(w0.x,xv.x,fmaf(w0.y,xv.y,fmaf(w0.z,xv.z,fmaf(w0.w,xv.w,ax0[s]))));
                ax1[s]=fmaf(w1.x,xv.x,fmaf(w1.y,xv.y,fmaf(w1.z,xv.z,fmaf(w1.w,xv.w,ax1[s]))));
                ax2[s]=fmaf(w2.x,xv.x,fmaf(w2.y,xv.y,fmaf(w2.z,xv.z,fmaf(w2.w,xv.w,ax2[s]))));
            }
        }
        float ah0[SPB]={0,0,0,0}, ah1[SPB]={0,0,0,0}, ah2[SPB]={0,0,0,0};
        if (!(d[0]&&d[1]&&d[2]&&d[3])) {
            #pragma unroll 4
            for (int cc = 0; cc < H_/4; ++cc) {
                float4 w0=wh0[cc], w1=wh1[cc], w2=wh2[cc];
                #pragma unroll
                for (int s = 0; s < SPB; ++s) if (!d[s]) {
                    float4 hv = ((const float4*)hs[s])[cc];
                    ah0[s]=fmaf(w0.x,hv.x,fmaf(w0.y,hv.y,fmaf(w0.z,hv.z,fmaf(w0.w,hv.w,ah0[s]))));
                    ah1[s]=fmaf(w1.x,hv.x,fmaf(w1.y,hv.y,fmaf(w1.z,hv.z,fmaf(w1.w,hv.w,ah1[s]))));
                    ah2[s]=fmaf(w2.x,hv.x,fmaf(w2.y,hv.y,fmaf(w2.z,hv.z,fmaf(w2.w,hv.w,ah2[s]))));
                }
            }
        }
        float hnew[SPB];
        #pragma unroll
        for (int s = 0; s < SPB; ++s) {
            float hpv = d[s] ? 0.0f : hreg[s];
            float r = sigmoidf_(ax0[s] + bi0 + ah0[s] + bh0);
            float z = sigmoidf_(ax1[s] + bi1 + ah1[s] + bh1);
            float n = tanhf_(ax2[s] + bi2 + r * (ah2[s] + bh2));
            hnew[s] = (1.0f - z) * n + z * hpv;
        }
        __syncthreads();
        #pragma unroll
        for (int s = 0; s < SPB; ++s) {
            hs[s][j] = hnew[s]; hreg[s] = hnew[s];
            out[(size_t)((size_t)t*BN_ + bn0 + s) * H_ + j] = hnew[s];
        }
    }
    #pragma unroll
    for (int s = 0; s < SPB; ++s)
        out[(size_t)T_*BN_*H_ + (size_t)(bn0+s)*H_ + j] = hreg[s];
}

extern "C" void kernel_launch(void* const* d_in, const int* in_sizes, int n_in,
                              void* d_out, int out_size, void* d_ws, size_t ws_size,
                              hipStream_t stream) {
    const float* x     = (const float*)d_in[0];
    const int*   dones = (const int*)  d_in[1];
    const float* h0    = (const float*)d_in[2];
    const float* W_ih  = (const float*)d_in[3];
    const float* W_hh  = (const float*)d_in[4];
    const float* b_ih  = (const float*)d_in[5];
    const float* b_hh  = (const float*)d_in[6];
    float*       out   = (float*)d_out;

    if (ws_size >= WS_NEED) {
        char* ws = (char*)d_ws;
        float*          h1  = (float*)(ws + OFF_H1);
        float*          hin = (float*)(ws + OFF_HIN);
        unsigned short* wbf = (unsigned short*)(ws + OFF_WBF);
        unsigned int*   dmm = (unsigned int*)(ws + OFF_DM);
        unsigned short* xg2 = (unsigned short*)(ws + OFF_XG);

        hipLaunchKernelGGL(xg2v2_kernel, dim3(8192 + 208), dim3(256), 0, stream,
                           x, W_ih, b_ih, b_hh, W_hh, dones, xg2, wbf, dmm);
        hipLaunchKernelGGL(pass1_kernel, dim3((NC_ - 1) * 32), dim3(256), 0, stream,
                           xg2, dmm, wbf, b_hh, h1);
        hipLaunchKernelGGL(pass2_kernel, dim3(BN_), dim3(256), 0, stream,
                           xg2, dmm, wbf, b_hh, h0, h1, hin);
        hipLaunchKernelGGL(pass3_kernel, dim3(NC_ * 32), dim3(256), 0, stream,
                           xg2, dmm, wbf, b_hh, hin, out);
    } else {
        hipLaunchKernelGGL(slotgru_fallback, dim3(BN_ / SPB), dim3(256), 0, stream,
                           x, dones, h0, W_ih, W_hh, b_ih, b_hh, out);
    }
}

// Round 11
// 311.181 us; speedup vs baseline: 2.2447x; 1.5467x over previous
//
#include <hip/hip_runtime.h>
#include <math.h>

#define T_   256
#define B_   32
#define N_   16
#define F_   128
#define H_   256
#define BN_  512          // B*N
#define G3_  768          // 3*H
#define CL_  32           // chunk length
#define NC_  8            // number of chunks (T_/CL_)

typedef __attribute__((ext_vector_type(8))) short  bf16x8;
typedef __attribute__((ext_vector_type(4))) float  f32x4;
typedef __attribute__((ext_vector_type(4))) unsigned short u16x4;

// ---- workspace layout (bytes) ----  (identical to round 6)
#define OFF_H1   0ULL                                   // f32 [NC][BN][H]   4 MB
#define OFF_HIN  4194304ULL                             // f32 [NC][BN][H]   4 MB
#define OFF_WBF  8388608ULL                             // bf16 [768][256]   384 KB
#define OFF_DM   8781824ULL                             // u32 [NC][BN]      16 KB
#define OFF_XG   8798208ULL                             // bf16 xg2 tiled    192 MB
#define WS_NEED  210124800ULL

__device__ __forceinline__ unsigned short f2bf(float f) {   // RNE float->bf16
    union { float f; unsigned u; } v; v.f = f;
    unsigned u = v.u + 0x7FFFu + ((v.u >> 16) & 1u);
    return (unsigned short)(u >> 16);
}
__device__ __forceinline__ float bf2f(unsigned short h) {
    union { unsigned u; float f; } v; v.u = ((unsigned)h) << 16;
    return v.f;
}
__device__ __forceinline__ bf16x8 load_pack8(const float* __restrict__ p) {
    f32x4 a = *(const f32x4*)p;
    f32x4 b = *(const f32x4*)(p + 4);
    bf16x8 r;
    r[0]=(short)f2bf(a[0]); r[1]=(short)f2bf(a[1]); r[2]=(short)f2bf(a[2]); r[3]=(short)f2bf(a[3]);
    r[4]=(short)f2bf(b[0]); r[5]=(short)f2bf(b[1]); r[6]=(short)f2bf(b[2]); r[7]=(short)f2bf(b[3]);
    return r;
}
__device__ __forceinline__ float sigmoidf_(float x) { return 1.0f / (1.0f + __expf(-x)); }
__device__ __forceinline__ float tanhf_(float x)    { return 1.0f - 2.0f / (__expf(2.0f * x) + 1.0f); }

// Pin a bf16x8 fragment to the AGPR class (empty asm; builtin MFMA reads A
// from AGPR directly — AV operand class — with compiler-managed hazards).
__device__ __forceinline__ bf16x8 pin_a(bf16x8 v) {
    bf16x8 r;
    asm("" : "=a"(r) : "0"(v));
    return r;
}

// xg2 tiled layout: u16 index for element (tt, seq, g)
__device__ __forceinline__ size_t xg2_idx(int tt, int seq, int g) {
    return ((((size_t)tt * 32 + (seq >> 4)) * 48 + (g >> 4)) * 64
            + ((g >> 2) & 3) * 16 + (seq & 15)) * 4 + (g & 3);
}

// ---------------------------------------------------------------------------
// xg3: pipelined input-projection GEMM. 256 persistent compute blocks
// (1/CU, 512 thr) each own one timestep t and process its 4 128-seq tiles
// with double-buffered LDS: loads of tile i+1 issue BEFORE compute of tile i
// (HBM latency hides under 192 MFMA/wave), convert+ds_write after compute.
// Output layout bit-identical to round 6. Blocks >= 256: fused prep.
// ---------------------------------------------------------------------------
__global__ __launch_bounds__(512, 2)
void xg3_kernel(const float* __restrict__ x, const float* __restrict__ W_ih,
                const float* __restrict__ b_ih, const float* __restrict__ b_hh,
                const float* __restrict__ W_hh, const int* __restrict__ dones,
                unsigned short* __restrict__ xg2,
                unsigned short* __restrict__ wbf, unsigned int* __restrict__ dm)
{
    const int tid = threadIdx.x;
    if (blockIdx.x >= 256) {                        // ---- fused prep ----
        const int bid2 = blockIdx.x - 256;
        if (bid2 < 96) {                            // W_hh f32 -> bf16
            const int i4 = bid2 * 512 + tid;        // 49152 f32x4 units
            f32x4 w = ((const f32x4*)W_hh)[i4];
            u16x4 o;
            #pragma unroll
            for (int q = 0; q < 4; ++q) o[q] = f2bf(w[q]);
            ((u16x4*)wbf)[i4] = o;
        } else {                                    // done masks (u32, CL=32)
            const int u = (bid2 - 96) * 512 + tid;  // 4096 = NC*BN
            const int c = u >> 9, s = u & 511;
            unsigned m = 0;
            #pragma unroll
            for (int k = 0; k < CL_; ++k)
                m |= (dones[(c * CL_ + k) * BN_ + s] ? 1u : 0u) << k;
            dm[c * BN_ + s] = m;
        }
        return;
    }

    __shared__ __align__(16) unsigned short xls[2][128][136];   // 69.6 KB dbuf

    const int wave = tid >> 6, lane = tid & 63;
    const int lr = lane & 15, lg = lane >> 4;
    const int t  = blockIdx.x;                      // one timestep per block
    const int g0 = wave * 96;

    // W_ih A-fragments (register-stationary for all 4 tiles) + biases
    bf16x8 wf[6][4];
    #pragma unroll
    for (int gt = 0; gt < 6; ++gt)
        #pragma unroll
        for (int kt = 0; kt < 4; ++kt)
            wf[gt][kt] = load_pack8(W_ih + (size_t)(g0 + gt*16 + lr) * F_ + kt*32 + lg*8);

    float bv[6][4];
    #pragma unroll
    for (int gt = 0; gt < 6; ++gt)
        #pragma unroll
        for (int q = 0; q < 4; ++q) {
            const int g = g0 + gt*16 + lg*4 + q;
            bv[gt][q] = b_ih[g] + (g < 2*H_ ? b_hh[g] : 0.0f);
        }

    // prologue: stage tile 0 (64 KB contiguous f32 read -> bf16 LDS)
    {
        f32x4 sv0[8];
        #pragma unroll
        for (int s = 0; s < 8; ++s)
            sv0[s] = ((const f32x4*)x)[(size_t)t * 16384 + s*512 + tid];
        #pragma unroll
        for (int s = 0; s < 8; ++s) {
            u16x4 o;
            #pragma unroll
            for (int q = 0; q < 4; ++q) o[q] = f2bf(sv0[s][q]);
            const int u = s*512 + tid;
            *(u16x4*)&xls[0][u >> 5][(u & 31) * 4] = o;
        }
    }
    __syncthreads();

    int buf = 0;
    #pragma unroll 1
    for (int i = 0; i < 4; ++i) {
        // 1. issue tile i+1 loads NOW (in flight under compute of tile i)
        f32x4 sv[8];
        if (i < 3) {
            #pragma unroll
            for (int s = 0; s < 8; ++s)
                sv[s] = ((const f32x4*)x)[(size_t)t * 16384 + (i+1)*4096 + s*512 + tid];
        }

        // 2. compute tile i: 8 seq-subtiles x (4 LDS frags, 24 MFMA, 6 stores)
        #pragma unroll
        for (int tbt = 0; tbt < 8; ++tbt) {
            bf16x8 xf[4];
            #pragma unroll
            for (int kt = 0; kt < 4; ++kt)
                xf[kt] = *(const bf16x8*)&xls[buf][tbt*16 + lr][kt*32 + lg*8];

            f32x4 acc[6];
            #pragma unroll
            for (int gt = 0; gt < 6; ++gt) acc[gt] = (f32x4){0.f, 0.f, 0.f, 0.f};

            #pragma unroll
            for (int kt = 0; kt < 4; ++kt)
                #pragma unroll
                for (int gt = 0; gt < 6; ++gt)
                    acc[gt] = __builtin_amdgcn_mfma_f32_16x16x32_bf16(wf[gt][kt], xf[kt], acc[gt], 0, 0, 0);

            const int sbg = i*8 + tbt;              // global 16-seq subtile
            #pragma unroll
            for (int gt = 0; gt < 6; ++gt) {
                u16x4 o;
                #pragma unroll
                for (int q = 0; q < 4; ++q) o[q] = f2bf(acc[gt][q] + bv[gt][q]);
                const size_t base = (((size_t)t * 32 + sbg) * 48 + (wave*6 + gt)) * 64 + lane;
                *(u16x4*)(xg2 + base * 4) = o;
            }
        }

        // 3. convert + write staged tile i+1 into the other buffer
        if (i < 3) {
            #pragma unroll
            for (int s = 0; s < 8; ++s) {
                u16x4 o;
                #pragma unroll
                for (int q = 0; q < 4; ++q) o[q] = f2bf(sv[s][q]);
                const int u = s*512 + tid;
                *(u16x4*)&xls[buf ^ 1][u >> 5][(u & 31) * 4] = o;
            }
            __syncthreads();
        }
        buf ^= 1;
    }
}

// ---------------------------------------------------------------------------
// Recurrent core (round-6 proven): 256 thr = 4 waves, 1 block/CU.
// Wave w owns j in [64w, 64w+64): r+z weights (64 frags) pinned to AGPR,
// n-gate (32 frags) in VGPRs. Weights loaded ONCE per block.
// ---------------------------------------------------------------------------
__global__ __launch_bounds__(256, 1)
void pass1_kernel(const unsigned short* __restrict__ xg2,
                  const unsigned int*  __restrict__ dm,
                  const unsigned short* __restrict__ wbf,
                  const float* __restrict__ b_hh,
                  float* __restrict__ h1)
{
    __shared__ __align__(16) unsigned short hT[2][8][4][16][8];   // 16 KB
    __shared__ __align__(16) float hpL[16][260];                  // 16.6 KB
    __shared__ float bhnL[H_];                                    // 1 KB

    const int tid  = threadIdx.x;
    const int wave = tid >> 6, lane = tid & 63;
    const int lr = lane & 15, lg = lane >> 4;
    const int c   = blockIdx.x >> 5;            // 0..NC_-2
    const int bn0 = (blockIdx.x & 31) * 16;
    const int jb  = wave * 64;

    const unsigned m = dm[c * BN_ + bn0 + lr];
    if (__ballot(m != 0) == 0ULL) return;       // uniform across waves

    int last = m ? (31 - __builtin_clz(m)) : 31;
    #pragma unroll
    for (int w = 1; w < 16; w <<= 1) last = min(last, __shfl_xor(last, w));

    bhnL[tid] = b_hh[2*H_ + tid];
    #pragma unroll
    for (int sweep = 0; sweep < 2; ++sweep)
        ((bf16x8*)hT)[sweep * 256 + tid] = (bf16x8)(short)0;
    #pragma unroll
    for (int sweep = 0; sweep < 4; ++sweep) {
        const int u = sweep * 256 + tid, seq = u >> 6, jq = u & 63;
        *(f32x4*)&hpL[seq][jq * 4] = (f32x4){0.f, 0.f, 0.f, 0.f};
    }

    // r+z gate weights -> AGPR (pinned); n gate -> VGPR
    bf16x8 wfa[8][8];   // mt = g*4+ms, g in {0(r),1(z)}
    bf16x8 wfv[4][8];   // n gate
    #pragma unroll
    for (int mt = 0; mt < 8; ++mt) {
        const int row = (mt >> 2) * H_ + jb + (mt & 3) * 16 + lr;
        #pragma unroll
        for (int kt = 0; kt < 8; ++kt)
            wfa[mt][kt] = pin_a(*(const bf16x8*)(wbf + (size_t)row * H_ + kt*32 + lg*8));
    }
    #pragma unroll
    for (int ms = 0; ms < 4; ++ms) {
        const int row = 2 * H_ + jb + ms * 16 + lr;
        #pragma unroll
        for (int kt = 0; kt < 8; ++kt)
            wfv[ms][kt] = *(const bf16x8*)(wbf + (size_t)row * H_ + kt*32 + lg*8);
    }
    __syncthreads();

    const int sb = bn0 >> 4;
    int buf = 0;
    for (int t = last; t < CL_; ++t) {
        const int tt = c * CL_ + t;
        const int tb = (tt * 32 + sb) * 48;

        u16x4 xv[3][4];
        #pragma unroll
        for (int g = 0; g < 3; ++g)
            #pragma unroll
            for (int ms = 0; ms < 4; ++ms)
                xv[g][ms] = ((const u16x4*)xg2)[(size_t)(tb + g*16 + wave*4 + ms) * 64 + lane];

        const int d = (m >> t) & 1;
        const short dms = (short)(d ? 0 : -1);

        f32x4 acc[12];
        #pragma unroll
        for (int mt = 0; mt < 8; ++mt) acc[mt] = (f32x4){0.f, 0.f, 0.f, 0.f};
        #pragma unroll
        for (int ms = 0; ms < 4; ++ms)                 // n-gate seeded with b_hh_n
            acc[8 + ms] = *(const f32x4*)&bhnL[jb + ms*16 + lg*4];

        #pragma unroll
        for (int kt = 0; kt < 8; ++kt) {
            bf16x8 hv = *(const bf16x8*)&hT[buf][kt][lg][lr][0];
            hv = hv & dms;
            #pragma unroll
            for (int mt = 0; mt < 8; ++mt)
                acc[mt] = __builtin_amdgcn_mfma_f32_16x16x32_bf16(wfa[mt][kt], hv, acc[mt], 0, 0, 0);
            #pragma unroll
            for (int ms = 0; ms < 4; ++ms)
                acc[8 + ms] = __builtin_amdgcn_mfma_f32_16x16x32_bf16(wfv[ms][kt], hv, acc[8 + ms], 0, 0, 0);
        }

        #pragma unroll
        for (int ms = 0; ms < 4; ++ms) {
            const int jq = jb + ms*16 + lg*4;
            f32x4 hp4 = *(const f32x4*)&hpL[lr][jq];
            f32x4 hnew4; u16x4 hb;
            #pragma unroll
            for (int q = 0; q < 4; ++q) {
                float r = sigmoidf_(acc[0 + ms][q] + bf2f(xv[0][ms][q]));
                float z = sigmoidf_(acc[4 + ms][q] + bf2f(xv[1][ms][q]));
                float n = tanhf_(bf2f(xv[2][ms][q]) + r * acc[8 + ms][q]);
                float hpv = d ? 0.0f : hp4[q];
                float hn2 = n + z * (hpv - n);
                hnew4[q] = hn2; hb[q] = f2bf(hn2);
            }
            *(f32x4*)&hpL[lr][jq] = hnew4;
            *(u16x4*)&hT[buf ^ 1][jq >> 5][(jq >> 3) & 3][lr][jq & 7] = hb;
        }
        __syncthreads();
        buf ^= 1;
    }

    #pragma unroll
    for (int ms = 0; ms < 4; ++ms) {
        const int jq = jb + ms*16 + lg*4;
        f32x4 hv = *(const f32x4*)&hpL[lr][jq];
        *(f32x4*)(h1 + ((size_t)c * BN_ + bn0 + lr) * H_ + jq) = hv;
    }
}

// ---------------------------------------------------------------------------
// pass2: chain h across chunks. Copy when chunk has a done; rare VALU GRU.
// ---------------------------------------------------------------------------
__global__ __launch_bounds__(256)
void pass2_kernel(const unsigned short* __restrict__ xg2,
                  const unsigned int*  __restrict__ dm,
                  const unsigned short* __restrict__ wbf,
                  const float* __restrict__ b_hh,
                  const float* __restrict__ h0,
                  const float* __restrict__ h1,
                  float* __restrict__ hin)
{
    __shared__ unsigned short hsb[H_];
    const int s = blockIdx.x, j = threadIdx.x;
    float h = h0[(size_t)s * H_ + j];
    const float bhn = b_hh[2*H_ + j];

    for (int c = 0; c < NC_; ++c) {
        hin[((size_t)c * BN_ + s) * H_ + j] = h;
        if (c == NC_ - 1) break;
        const unsigned m = dm[c * BN_ + s];         // block-uniform
        if (m) {
            h = h1[((size_t)c * BN_ + s) * H_ + j];
        } else {
            for (int t = 0; t < CL_; ++t) {
                hsb[j] = f2bf(h);
                __syncthreads();
                float a0 = 0.f, a1 = 0.f, a2 = 0.f;
                for (int k = 0; k < H_; ++k) {
                    float hk = bf2f(hsb[k]);
                    a0 = fmaf(bf2f(wbf[(size_t)j * H_ + k]),          hk, a0);
                    a1 = fmaf(bf2f(wbf[(size_t)(H_ + j) * H_ + k]),   hk, a1);
                    a2 = fmaf(bf2f(wbf[(size_t)(2*H_ + j) * H_ + k]), hk, a2);
                }
                const int tt = c * CL_ + t;
                float xr = bf2f(xg2[xg2_idx(tt, s, j)]);
                float xz = bf2f(xg2[xg2_idx(tt, s, H_ + j)]);
                float xn = bf2f(xg2[xg2_idx(tt, s, 2*H_ + j)]);
                float r = sigmoidf_(a0 + xr);
                float z = sigmoidf_(a1 + xz);
                float n = tanhf_(xn + r * (a2 + bhn));
                h = n + z * (h - n);
                __syncthreads();
            }
        }
    }
}

// ---------------------------------------------------------------------------
// pass3: from known h_in, compute all outputs. Round-6 core (proven 182 us).
// ---------------------------------------------------------------------------
__global__ __launch_bounds__(256, 1)
void pass3_kernel(const unsigned short* __restrict__ xg2,
                  const unsigned int*  __restrict__ dm,
                  const unsigned short* __restrict__ wbf,
                  const float* __restrict__ b_hh,
                  const float* __restrict__ hin,
                  float* __restrict__ out)
{
    __shared__ __align__(16) unsigned short hT[2][8][4][16][8];   // 16 KB
    __shared__ __align__(16) float hpL[16][260];                  // 16.6 KB
    __shared__ float bhnL[H_];                                    // 1 KB

    const int tid  = threadIdx.x;
    const int wave = tid >> 6, lane = tid & 63;
    const int lr = lane & 15, lg = lane >> 4;
    const int c   = blockIdx.x >> 5;            // 0..NC_-1
    const int bn0 = (blockIdx.x & 31) * 16;
    const int jb  = wave * 64;

    const unsigned m = dm[c * BN_ + bn0 + lr];

    bhnL[tid] = b_hh[2*H_ + tid];
    // stage h_in: f32 -> hpL, bf16 -> hT[0]
    #pragma unroll
    for (int sweep = 0; sweep < 4; ++sweep) {
        const int u = sweep * 256 + tid, seq = u >> 6, jq = u & 63;
        f32x4 hv = ((const f32x4*)hin)[((size_t)c * BN_ + bn0 + seq) * 64 + jq];
        *(f32x4*)&hpL[seq][jq * 4] = hv;
    }
    #pragma unroll
    for (int sweep = 0; sweep < 2; ++sweep) {
        const int u = sweep * 256 + tid, col = u & 15, kb = (u >> 4) * 8;
        bf16x8 hv = load_pack8(hin + ((size_t)c * BN_ + bn0 + col) * H_ + kb);
        ((bf16x8*)hT)[u] = hv;
    }

    bf16x8 wfa[8][8];
    bf16x8 wfv[4][8];
    #pragma unroll
    for (int mt = 0; mt < 8; ++mt) {
        const int row = (mt >> 2) * H_ + jb + (mt & 3) * 16 + lr;
        #pragma unroll
        for (int kt = 0; kt < 8; ++kt)
            wfa[mt][kt] = pin_a(*(const bf16x8*)(wbf + (size_t)row * H_ + kt*32 + lg*8));
    }
    #pragma unroll
    for (int ms = 0; ms < 4; ++ms) {
        const int row = 2 * H_ + jb + ms * 16 + lr;
        #pragma unroll
        for (int kt = 0; kt < 8; ++kt)
            wfv[ms][kt] = *(const bf16x8*)(wbf + (size_t)row * H_ + kt*32 + lg*8);
    }
    __syncthreads();

    const int sb = bn0 >> 4;
    int buf = 0;
    for (int t = 0; t < CL_; ++t) {
        const int tt = c * CL_ + t;
        const int tb = (tt * 32 + sb) * 48;

        u16x4 xv[3][4];
        #pragma unroll
        for (int g = 0; g < 3; ++g)
            #pragma unroll
            for (int ms = 0; ms < 4; ++ms)
                xv[g][ms] = ((const u16x4*)xg2)[(size_t)(tb + g*16 + wave*4 + ms) * 64 + lane];

        const int d = (m >> t) & 1;
        const short dms = (short)(d ? 0 : -1);

        f32x4 acc[12];
        #pragma unroll
        for (int mt = 0; mt < 8; ++mt) acc[mt] = (f32x4){0.f, 0.f, 0.f, 0.f};
        #pragma unroll
        for (int ms = 0; ms < 4; ++ms)                 // n-gate seeded with b_hh_n
            acc[8 + ms] = *(const f32x4*)&bhnL[jb + ms*16 + lg*4];

        #pragma unroll
        for (int kt = 0; kt < 8; ++kt) {
            bf16x8 hv = *(const bf16x8*)&hT[buf][kt][lg][lr][0];
            hv = hv & dms;
            #pragma unroll
            for (int mt = 0; mt < 8; ++mt)
                acc[mt] = __builtin_amdgcn_mfma_f32_16x16x32_bf16(wfa[mt][kt], hv, acc[mt], 0, 0, 0);
            #pragma unroll
            for (int ms = 0; ms < 4; ++ms)
                acc[8 + ms] = __builtin_amdgcn_mfma_f32_16x16x32_bf16(wfv[ms][kt], hv, acc[8 + ms], 0, 0, 0);
        }

        #pragma unroll
        for (int ms = 0; ms < 4; ++ms) {
            const int jq = jb + ms*16 + lg*4;
            f32x4 hp4 = *(const f32x4*)&hpL[lr][jq];
            f32x4 hnew4; u16x4 hb;
            #pragma unroll
            for (int q = 0; q < 4; ++q) {
                float r = sigmoidf_(acc[0 + ms][q] + bf2f(xv[0][ms][q]));
                float z = sigmoidf_(acc[4 + ms][q] + bf2f(xv[1][ms][q]));
                float n = tanhf_(bf2f(xv[2][ms][q]) + r * acc[8 + ms][q]);
                float hpv = d ? 0.0f : hp4[q];
                float hn2 = n + z * (hpv - n);
                hnew4[q] = hn2; hb[q] = f2bf(hn2);
            }
            *(f32x4*)&hpL[lr][jq] = hnew4;
            *(u16x4*)&hT[buf ^ 1][jq >> 5][(jq >> 3) & 3][lr][jq & 7] = hb;
            *(f32x4*)(out + ((size_t)tt * BN_ + bn0 + lr) * H_ + jq) = hnew4;
        }
        __syncthreads();
        buf ^= 1;
    }

    if (c == NC_ - 1) {
        #pragma unroll
        for (int ms = 0; ms < 4; ++ms) {
            const int jq = jb + ms*16 + lg*4;
            f32x4 hv = *(const f32x4*)&hpL[lr][jq];
            *(f32x4*)(out + (size_t)T_ * BN_ * H_ + (size_t)(bn0 + lr) * H_ + jq) = hv;
        }
    }
}

// ---------------------------------------------------------------------------
// Fallback (ws too small): fp32 VALU persistent kernel (correct, slow)
// ---------------------------------------------------------------------------
#define SPB 4
__global__ __launch_bounds__(256, 1)
void slotgru_fallback(const float* __restrict__ x, const int* __restrict__ dones,
                      const float* __restrict__ h0, const float* __restrict__ W_ih,
                      const float* __restrict__ W_hh, const float* __restrict__ b_ih,
                      const float* __restrict__ b_hh, float* __restrict__ out)
{
    __shared__ __align__(16) float xs[SPB][F_];
    __shared__ __align__(16) float hs[SPB][H_];
    const int j = threadIdx.x, bn0 = blockIdx.x * SPB;
    const float bi0 = b_ih[j], bi1 = b_ih[H_ + j], bi2 = b_ih[2*H_ + j];
    const float bh0 = b_hh[j], bh1 = b_hh[H_ + j], bh2 = b_hh[2*H_ + j];
    const float4* wi0 = (const float4*)(W_ih + (size_t)j * F_);
    const float4* wi1 = (const float4*)(W_ih + (size_t)(H_ + j) * F_);
    const float4* wi2 = (const float4*)(W_ih + (size_t)(2*H_ + j) * F_);
    const float4* wh0 = (const float4*)(W_hh + (size_t)j * H_);
    const float4* wh1 = (const float4*)(W_hh + (size_t)(H_ + j) * H_);
    const float4* wh2 = (const float4*)(W_hh + (size_t)(2*H_ + j) * H_);
    float hreg[SPB];
    #pragma unroll
    for (int s = 0; s < SPB; ++s) { float h = h0[(size_t)(bn0+s)*H_ + j]; hreg[s]=h; hs[s][j]=h; }
    for (int t = 0; t < T_; ++t) {
        int d[SPB];
        #pragma unroll
        for (int s = 0; s < SPB; ++s) d[s] = dones[(size_t)t*BN_ + bn0 + s];
        const float* xsrc = x + (size_t)((size_t)t*BN_ + bn0) * F_;
        ((float*)xs)[j] = xsrc[j]; ((float*)xs)[j+256] = xsrc[j+256];
        #pragma unroll
        for (int s = 0; s < SPB; ++s) if (d[s]) hs[s][j] = 0.0f;
        __syncthreads();
        float ax0[SPB]={0,0,0,0}, ax1[SPB]={0,0,0,0}, ax2[SPB]={0,0,0,0};
        #pragma unroll 8
        for (int cc = 0; cc < F_/4; ++cc) {
            float4 w0=wi0[cc], w1=wi1[cc], w2=wi2[cc];
            #pragma unroll
            for (int s = 0; s < SPB; ++s) {
                float4 xv = ((const float4*)xs[s])[cc];
                ax0[s]=fmaf(w0.x,xv.x,fmaf(w0.y,xv.y,fmaf(w0.z,xv.z,fmaf(w0.w,xv.w,ax0[s]))));
                ax1[s]=fmaf(w1.x,xv.x,fmaf(w1.y,xv.y,fmaf(w1.z,xv.z,fmaf(w1.w,xv.w,ax1[s]))));
                ax2[s]=fmaf(w2.x,xv.x,fmaf(w2.y,xv.y,fmaf(w2.z,xv.z,fmaf(w2.w,xv.w,ax2[s]))));
            }
        }
        float ah0[SPB]={0,0,0,0}, ah1[SPB]={0,0,0,0}, ah2[SPB]={0,0,0,0};
        if (!(d[0]&&d[1]&&d[2]&&d[3])) {
            #pragma unroll 4
            for (int cc = 0; cc < H_/4; ++cc) {
                float4 w0=wh0[cc], w1=wh1[cc], w2=wh2[cc];
                #pragma unroll
                for (int s = 0; s < SPB; ++s) if (!d[s]) {
                    float4 hv = ((const float4*)hs[s])[cc];
                    ah0[s]=fmaf(w0.x,hv.x,fmaf(w0.y,hv.y,fmaf(w0.z,hv.z,fmaf(w0.w,hv.w,ah0[s]))));
                    ah1[s]=fmaf(w1.x,hv.x,fmaf(w1.y,hv.y,fmaf(w1.z,hv.z,fmaf(w1.w,hv.w,ah1[s]))));
                    ah2[s]=fmaf(w2.x,hv.x,fmaf(w2.y,hv.y,fmaf(w2.z,hv.z,fmaf(w2.w,hv.w,ah2[s]))));
                }
            }
        }
        float hnew[SPB];
        #pragma unroll
        for (int s = 0; s < SPB; ++s) {
            float hpv = d[s] ? 0.0f : hreg[s];
            float r = sigmoidf_(ax0[s] + bi0 + ah0[s] + bh0);
            float z = sigmoidf_(ax1[s] + bi1 + ah1[s] + bh1);
            float n = tanhf_(ax2[s] + bi2 + r * (ah2[s] + bh2));
            hnew[s] = (1.0f - z) * n + z * hpv;
        }
        __syncthreads();
        #pragma unroll
        for (int s = 0; s < SPB; ++s) {
            hs[s][j] = hnew[s]; hreg[s] = hnew[s];
            out[(size_t)((size_t)t*BN_ + bn0 + s) * H_ + j] = hnew[s];
        }
    }
    #pragma unroll
    for (int s = 0; s < SPB; ++s)
        out[(size_t)T_*BN_*H_ + (size_t)(bn0+s)*H_ + j] = hreg[s];
}

extern "C" void kernel_launch(void* const* d_in, const int* in_sizes, int n_in,
                              void* d_out, int out_size, void* d_ws, size_t ws_size,
                              hipStream_t stream) {
    const float* x     = (const float*)d_in[0];
    const int*   dones = (const int*)  d_in[1];
    const float* h0    = (const float*)d_in[2];
    const float* W_ih  = (const float*)d_in[3];
    const float* W_hh  = (const float*)d_in[4];
    const float* b_ih  = (const float*)d_in[5];
    const float* b_hh  = (const float*)d_in[6];
    float*       out   = (float*)d_out;

    if (ws_size >= WS_NEED) {
        char* ws = (char*)d_ws;
        float*          h1  = (float*)(ws + OFF_H1);
        float*          hin = (float*)(ws + OFF_HIN);
        unsigned short* wbf = (unsigned short*)(ws + OFF_WBF);
        unsigned int*   dmm = (unsigned int*)(ws + OFF_DM);
        unsigned short* xg2 = (unsigned short*)(ws + OFF_XG);

        hipLaunchKernelGGL(xg3_kernel, dim3(256 + 104), dim3(512), 0, stream,
                           x, W_ih, b_ih, b_hh, W_hh, dones, xg2, wbf, dmm);
        hipLaunchKernelGGL(pass1_kernel, dim3((NC_ - 1) * 32), dim3(256), 0, stream,
                           xg2, dmm, wbf, b_hh, h1);
        hipLaunchKernelGGL(pass2_kernel, dim3(BN_), dim3(256), 0, stream,
                           xg2, dmm, wbf, b_hh, h0, h1, hin);
        hipLaunchKernelGGL(pass3_kernel, dim3(NC_ * 32), dim3(256), 0, stream,
                           xg2, dmm, wbf, b_hh, hin, out);
    } else {
        hipLaunchKernelGGL(slotgru_fallback, dim3(BN_ / SPB), dim3(256), 0, stream,
                           x, dones, h0, W_ih, W_hh, b_ih, b_hh, out);
    }
}